// Round 1
// baseline (1295.436 us; speedup 1.0000x reference)
//
#include <hip/hip_runtime.h>
#include <hip/hip_bf16.h>

// ---------------------------------------------------------------------------
// 3-layer GCN: per layer  t = act(h) @ W ;  h' = A_norm @ t + b
// A_norm = D^-1/2 (A + I) D^-1/2, built once as CSR-by-dst with premultiplied
// edge weights. BN+leaky fused into next GEMM's A load. Final layer fuses
// bias + L2 row-normalize.
// ---------------------------------------------------------------------------

__global__ void k_init(float* __restrict__ deg, int* __restrict__ count,
                       float* __restrict__ bnsum, int n) {
  int i = blockIdx.x * 256 + threadIdx.x;
  if (i < n) { deg[i] = 1.0f; count[i] = 0; }   // deg starts at 1 (self-loop w=1)
  if (i < 512) bnsum[i] = 0.0f;                 // 2 layers x (sum[128]+sumsq[128])
}

__global__ void k_deg(const int* __restrict__ dst, const float* __restrict__ ew,
                      float* __restrict__ deg, int* __restrict__ count, int E) {
  int e = blockIdx.x * 256 + threadIdx.x;
  if (e < E) {
    int d = dst[e];
    atomicAdd(&deg[d], ew[e]);
    atomicAdd(&count[d], 1);
  }
}

__global__ void k_dis(const float* __restrict__ deg, float* __restrict__ dis, int n) {
  int i = blockIdx.x * 256 + threadIdx.x;
  if (i < n) dis[i] = rsqrtf(deg[i]);   // deg >= 1 always
}

// single-block exclusive scan of count[N] -> row_ptr[N+1]; also fills cursor
__global__ __launch_bounds__(1024) void k_scan(const int* __restrict__ count,
                                               int* __restrict__ row_ptr,
                                               int* __restrict__ cursor, int N) {
  __shared__ int ls[1024];
  int t = threadIdx.x;
  int C = (N + 1023) >> 10;
  int lo = t * C, hi = min(lo + C, N);
  int s = 0;
  for (int j = lo; j < hi; ++j) s += count[j];
  ls[t] = s;
  __syncthreads();
  for (int off = 1; off < 1024; off <<= 1) {
    int v = (t >= off) ? ls[t - off] : 0;
    __syncthreads();
    ls[t] += v;
    __syncthreads();
  }
  int run = (t > 0) ? ls[t - 1] : 0;
  for (int j = lo; j < hi; ++j) {
    row_ptr[j] = run; cursor[j] = run;
    run += count[j];
  }
  if (t == 1023) row_ptr[N] = ls[1023];
}

__global__ void k_scatter(const int* __restrict__ src, const int* __restrict__ dst,
                          const float* __restrict__ ew, const float* __restrict__ dis,
                          int* __restrict__ cursor, int* __restrict__ src_perm,
                          float* __restrict__ w_perm, int E) {
  int e = blockIdx.x * 256 + threadIdx.x;
  if (e < E) {
    int s = src[e], d = dst[e];
    int pos = atomicAdd(&cursor[d], 1);
    src_perm[pos] = s;
    w_perm[pos] = ew[e] * dis[s] * dis[d];
  }
}

// ---------------------------------------------------------------------------
// f32 GEMM: C[N,Dout] = act(A[N,K]) @ W[K,Dout]. 64x64 tile, BK=32,
// 256 thr, 4x4 microtile. Optional fused BN scale/shift + leaky(0.1) on A.
// ---------------------------------------------------------------------------
template <bool HAS_BN>
__global__ __launch_bounds__(256) void k_gemm(
    const float* __restrict__ A, const float* __restrict__ W,
    const float* __restrict__ sc, const float* __restrict__ sh,
    float* __restrict__ C, int N, int K, int Dout) {
  __shared__ float Ast[32][68];   // A tile transposed [k][m], pad 4 for b128 align
  __shared__ float Bs[32][64];
  const int tid = threadIdx.x;
  const int ty = tid >> 4, tx = tid & 15;
  const int brow = blockIdx.x * 64;
  const int bcol = blockIdx.y * 64;
  const int lm  = tid >> 3;         // 0..31 (A row within tile, +32 second)
  const int lc4 = (tid & 7) * 4;    // A col group
  const int bk  = tid >> 4;         // 0..15 (B k row, +16 second)
  const int bc4 = (tid & 15) * 4;

  float acc[4][4] = {};

  for (int k0 = 0; k0 < K; k0 += 32) {
#pragma unroll
    for (int h = 0; h < 2; ++h) {
      int m = lm + h * 32;
      int row = brow + m;
      float4 v = make_float4(0.f, 0.f, 0.f, 0.f);
      if (row < N)
        v = *reinterpret_cast<const float4*>(&A[(size_t)row * K + k0 + lc4]);
      if (HAS_BN) {
        float t;
        t = v.x * sc[k0 + lc4 + 0] + sh[k0 + lc4 + 0]; v.x = t > 0.f ? t : 0.1f * t;
        t = v.y * sc[k0 + lc4 + 1] + sh[k0 + lc4 + 1]; v.y = t > 0.f ? t : 0.1f * t;
        t = v.z * sc[k0 + lc4 + 2] + sh[k0 + lc4 + 2]; v.z = t > 0.f ? t : 0.1f * t;
        t = v.w * sc[k0 + lc4 + 3] + sh[k0 + lc4 + 3]; v.w = t > 0.f ? t : 0.1f * t;
      }
      Ast[lc4 + 0][m] = v.x;
      Ast[lc4 + 1][m] = v.y;
      Ast[lc4 + 2][m] = v.z;
      Ast[lc4 + 3][m] = v.w;
    }
#pragma unroll
    for (int h = 0; h < 2; ++h) {
      int kk = bk + h * 16;
      *reinterpret_cast<float4*>(&Bs[kk][bc4]) =
          *reinterpret_cast<const float4*>(&W[(size_t)(k0 + kk) * Dout + bcol + bc4]);
    }
    __syncthreads();
#pragma unroll
    for (int kk = 0; kk < 32; ++kk) {
      float4 a4 = *reinterpret_cast<const float4*>(&Ast[kk][ty * 4]);
      float4 b4 = *reinterpret_cast<const float4*>(&Bs[kk][tx * 4]);
      float av[4] = {a4.x, a4.y, a4.z, a4.w};
      float bv[4] = {b4.x, b4.y, b4.z, b4.w};
#pragma unroll
      for (int i = 0; i < 4; ++i)
#pragma unroll
        for (int j = 0; j < 4; ++j) acc[i][j] += av[i] * bv[j];
    }
    __syncthreads();
  }
#pragma unroll
  for (int i = 0; i < 4; ++i) {
    int row = brow + ty * 4 + i;
    if (row < N) {
      float4 o = make_float4(acc[i][0], acc[i][1], acc[i][2], acc[i][3]);
      *reinterpret_cast<float4*>(&C[(size_t)row * Dout + bcol + tx * 4]) = o;
    }
  }
}

// ---------------------------------------------------------------------------
// aggregation D=128: one wave per node, 2 channels/lane. out = A_norm@t + b
// ---------------------------------------------------------------------------
__global__ __launch_bounds__(256) void k_agg128(
    const float* __restrict__ t, const int* __restrict__ row_ptr,
    const int* __restrict__ src_perm, const float* __restrict__ w_perm,
    const float* __restrict__ dis, const float* __restrict__ bias,
    float* __restrict__ out, int N) {
  int node = blockIdx.x * 4 + (threadIdx.x >> 6);
  int lane = threadIdx.x & 63;
  if (node >= N) return;
  float d = dis[node];
  float self = d * d;
  float acc0 = t[node * 128 + lane] * self;
  float acc1 = t[node * 128 + 64 + lane] * self;
  int beg = row_ptr[node], end = row_ptr[node + 1];
  for (int e = beg; e < end; ++e) {
    int s = src_perm[e];
    float w = w_perm[e];
    acc0 += w * t[s * 128 + lane];
    acc1 += w * t[s * 128 + 64 + lane];
  }
  out[node * 128 + lane] = acc0 + bias[lane];
  out[node * 128 + 64 + lane] = acc1 + bias[64 + lane];
}

// aggregation D=64 + bias + L2 row-normalize (final layer) -> d_out
__global__ __launch_bounds__(256) void k_agg64_norm(
    const float* __restrict__ t, const int* __restrict__ row_ptr,
    const int* __restrict__ src_perm, const float* __restrict__ w_perm,
    const float* __restrict__ dis, const float* __restrict__ b3,
    float* __restrict__ out, int N) {
  int node = blockIdx.x * 4 + (threadIdx.x >> 6);
  int lane = threadIdx.x & 63;
  if (node >= N) return;
  float d = dis[node];
  float acc = t[node * 64 + lane] * d * d;
  int beg = row_ptr[node], end = row_ptr[node + 1];
  for (int e = beg; e < end; ++e)
    acc += w_perm[e] * t[src_perm[e] * 64 + lane];
  acc += b3[lane];
  float sq = acc * acc;
#pragma unroll
  for (int off = 32; off; off >>= 1) sq += __shfl_xor(sq, off, 64);
  float nrm = sqrtf(sq);
  out[node * 64 + lane] = acc / fmaxf(nrm, 1e-12f);
}

// BN stats: partial sums per channel (128 ch), sums[0..127]=sum, [128..255]=sumsq
__global__ void k_bn_partial(const float* __restrict__ h, float* __restrict__ sums,
                             int N) {
  int c = threadIdx.x & 127;
  int half = threadIdx.x >> 7;
  float s = 0.f, q = 0.f;
  for (int r = blockIdx.x * 2 + half; r < N; r += gridDim.x * 2) {
    float v = h[(size_t)r * 128 + c];
    s += v; q += v * v;
  }
  atomicAdd(&sums[c], s);
  atomicAdd(&sums[128 + c], q);
}

__global__ void k_bn_final(const float* __restrict__ sums, const float* __restrict__ g,
                           const float* __restrict__ be, float* __restrict__ scsh,
                           int N) {
  int c = threadIdx.x;  // 128
  float inv_n = 1.0f / (float)N;
  float mu = sums[c] * inv_n;
  float var = sums[128 + c] * inv_n - mu * mu;
  float sc = g[c] * rsqrtf(var + 1e-5f);
  scsh[c] = sc;
  scsh[128 + c] = be[c] - mu * sc;
}

// ---------------------------------------------------------------------------

extern "C" void kernel_launch(void* const* d_in, const int* in_sizes, int n_in,
                              void* d_out, int out_size, void* d_ws, size_t ws_size,
                              hipStream_t stream) {
  const float* x  = (const float*)d_in[0];
  const int*   ei = (const int*)d_in[1];
  const float* ew = (const float*)d_in[2];
  const float* W1 = (const float*)d_in[3];
  const float* b1 = (const float*)d_in[4];
  const float* g1 = (const float*)d_in[5];
  const float* be1= (const float*)d_in[6];
  const float* W2 = (const float*)d_in[7];
  const float* b2 = (const float*)d_in[8];
  const float* g2 = (const float*)d_in[9];
  const float* be2= (const float*)d_in[10];
  const float* W3 = (const float*)d_in[11];
  const float* b3 = (const float*)d_in[12];

  const int N = in_sizes[0] / 128;   // 100000
  const int E = in_sizes[2];         // 1600000
  const int* src = ei;
  const int* dst = ei + E;

  // workspace partition (256B aligned)
  char* p = (char*)d_ws;
  auto alloc = [&](size_t bytes) -> void* {
    void* r = (void*)p;
    p += (bytes + 255) & ~(size_t)255;
    return r;
  };
  float* deg      = (float*)alloc((size_t)N * 4);
  float* dis      = (float*)alloc((size_t)N * 4);
  int*   count    = (int*)alloc((size_t)N * 4);
  int*   row_ptr  = (int*)alloc((size_t)(N + 1) * 4);
  int*   cursor   = (int*)alloc((size_t)N * 4);
  int*   src_perm = (int*)alloc((size_t)E * 4);
  float* w_perm   = (float*)alloc((size_t)E * 4);
  float* t_buf    = (float*)alloc((size_t)N * 128 * 4);
  float* h_buf    = (float*)alloc((size_t)N * 128 * 4);
  float* bnsum    = (float*)alloc(512 * 4);   // [0..255] layer1, [256..511] layer2
  float* scsh1    = (float*)alloc(256 * 4);
  float* scsh2    = (float*)alloc(256 * 4);
  (void)ws_size; (void)n_in; (void)out_size;

  const int gN = (N + 255) / 256;
  const int gE = (E + 255) / 256;
  const int rowBlocks = (N + 63) / 64;
  const int aggBlocks = (N + 3) / 4;

  // graph build (per-call: ws is re-poisoned)
  k_init<<<gN, 256, 0, stream>>>(deg, count, bnsum, N);
  k_deg<<<gE, 256, 0, stream>>>(dst, ew, deg, count, E);
  k_dis<<<gN, 256, 0, stream>>>(deg, dis, N);
  k_scan<<<1, 1024, 0, stream>>>(count, row_ptr, cursor, N);
  k_scatter<<<gE, 256, 0, stream>>>(src, dst, ew, dis, cursor, src_perm, w_perm, E);

  // layer 1
  k_gemm<false><<<dim3(rowBlocks, 2), 256, 0, stream>>>(x, W1, nullptr, nullptr,
                                                        t_buf, N, 128, 128);
  k_agg128<<<aggBlocks, 256, 0, stream>>>(t_buf, row_ptr, src_perm, w_perm, dis,
                                          b1, h_buf, N);
  k_bn_partial<<<512, 256, 0, stream>>>(h_buf, bnsum, N);
  k_bn_final<<<1, 128, 0, stream>>>(bnsum, g1, be1, scsh1, N);

  // layer 2 (BN1+leaky fused into GEMM A-load)
  k_gemm<true><<<dim3(rowBlocks, 2), 256, 0, stream>>>(h_buf, W2, scsh1, scsh1 + 128,
                                                       t_buf, N, 128, 128);
  k_agg128<<<aggBlocks, 256, 0, stream>>>(t_buf, row_ptr, src_perm, w_perm, dis,
                                          b2, h_buf, N);
  k_bn_partial<<<512, 256, 0, stream>>>(h_buf, bnsum + 256, N);
  k_bn_final<<<1, 128, 0, stream>>>(bnsum + 256, g2, be2, scsh2, N);

  // layer 3 (BN2+leaky fused into GEMM A-load), Dout=64, fused bias+L2 norm
  k_gemm<true><<<dim3(rowBlocks, 1), 256, 0, stream>>>(h_buf, W3, scsh2, scsh2 + 128,
                                                       t_buf, N, 128, 64);
  k_agg64_norm<<<aggBlocks, 256, 0, stream>>>(t_buf, row_ptr, src_perm, w_perm, dis,
                                              b3, (float*)d_out, N);
}

// Round 2
// 1038.623 us; speedup vs baseline: 1.2473x; 1.2473x over previous
//
#include <hip/hip_runtime.h>
#include <hip/hip_bf16.h>

// ---------------------------------------------------------------------------
// 3-layer GCN: per layer  t = act(h) @ W ;  h' = A_norm @ t + b
// A_norm = D^-1/2 (A + I) D^-1/2, built as CSR-by-dst with premultiplied
// edge weights. BN+leaky fused into next GEMM's A load. t stored bf16 to
// halve aggregation gather traffic; accumulation stays f32.
// ---------------------------------------------------------------------------

__global__ void k_init(float* __restrict__ deg, int* __restrict__ count,
                       float* __restrict__ bnsum, int n) {
  int i = blockIdx.x * 256 + threadIdx.x;
  if (i < n) { deg[i] = 1.0f; count[i] = 0; }   // deg starts at 1 (self-loop w=1)
  if (i < 512) bnsum[i] = 0.0f;
}

__global__ void k_deg(const int* __restrict__ dst, const float* __restrict__ ew,
                      float* __restrict__ deg, int* __restrict__ count, int E) {
  int e = blockIdx.x * 256 + threadIdx.x;
  if (e < E) {
    int d = dst[e];
    atomicAdd(&deg[d], ew[e]);
    atomicAdd(&count[d], 1);
  }
}

__global__ void k_dis(const float* __restrict__ deg, float* __restrict__ dis, int n) {
  int i = blockIdx.x * 256 + threadIdx.x;
  if (i < n) dis[i] = rsqrtf(deg[i]);
}

// --- hierarchical scan: count[N] -> row_ptr[N+1], cursor[N] ----------------
// phase 1: per-block (1024 elems) partial sums
__global__ __launch_bounds__(256) void k_scan_part(const int* __restrict__ count,
                                                   int* __restrict__ part, int N) {
  int base = blockIdx.x * 1024;
  int t = threadIdx.x;
  int s = 0;
  for (int j = base + t; j < min(base + 1024, N); j += 256) s += count[j];
#pragma unroll
  for (int off = 32; off; off >>= 1) s += __shfl_xor(s, off, 64);
  __shared__ int ws[4];
  if ((t & 63) == 0) ws[t >> 6] = s;
  __syncthreads();
  if (t == 0) part[blockIdx.x] = ws[0] + ws[1] + ws[2] + ws[3];
}

// phase 2: single block scans nb (<=256) partials in place -> exclusive offsets
__global__ __launch_bounds__(256) void k_scan_top(int* __restrict__ part, int nb,
                                                  int* __restrict__ total) {
  __shared__ int ls[256];
  int t = threadIdx.x;
  int v = (t < nb) ? part[t] : 0;
  ls[t] = v;
  __syncthreads();
  for (int off = 1; off < 256; off <<= 1) {
    int u = (t >= off) ? ls[t - off] : 0;
    __syncthreads();
    ls[t] += u;
    __syncthreads();
  }
  if (t < nb) part[t] = ls[t] - v;          // exclusive
  if (t == nb - 1) *total = ls[t];          // row_ptr[N]
}

// phase 3: per-block rescan (4 elems/thread) + offset, write row_ptr & cursor
__global__ __launch_bounds__(256) void k_scan_bot(const int* __restrict__ count,
                                                  const int* __restrict__ part,
                                                  int* __restrict__ row_ptr,
                                                  int* __restrict__ cursor, int N) {
  __shared__ int ls[256];
  int t = threadIdx.x;
  int idx = blockIdx.x * 1024 + t * 4;
  int c[4];
  int s = 0;
#pragma unroll
  for (int i = 0; i < 4; ++i) {
    int j = idx + i;
    c[i] = (j < N) ? count[j] : 0;
    s += c[i];
  }
  ls[t] = s;
  __syncthreads();
  for (int off = 1; off < 256; off <<= 1) {
    int u = (t >= off) ? ls[t - off] : 0;
    __syncthreads();
    ls[t] += u;
    __syncthreads();
  }
  int run = part[blockIdx.x] + ls[t] - s;   // exclusive prefix for this thread
#pragma unroll
  for (int i = 0; i < 4; ++i) {
    int j = idx + i;
    if (j < N) { row_ptr[j] = run; cursor[j] = run; run += c[i]; }
  }
}

__global__ void k_scatter(const int* __restrict__ src, const int* __restrict__ dst,
                          const float* __restrict__ ew, const float* __restrict__ dis,
                          int* __restrict__ cursor, int* __restrict__ src_perm,
                          float* __restrict__ w_perm, int E) {
  int e = blockIdx.x * 256 + threadIdx.x;
  if (e < E) {
    int s = src[e], d = dst[e];
    int pos = atomicAdd(&cursor[d], 1);
    src_perm[pos] = s;
    w_perm[pos] = ew[e] * dis[s] * dis[d];
  }
}

// ---------------------------------------------------------------------------
// f32 GEMM: C[N,Dout](bf16) = act(A[N,K]) @ W[K,Dout]. 64x64 tile, BK=32,
// 256 thr, 4x4 microtile. Optional fused BN scale/shift + leaky(0.1) on A.
// ---------------------------------------------------------------------------
template <bool HAS_BN>
__global__ __launch_bounds__(256) void k_gemm(
    const float* __restrict__ A, const float* __restrict__ W,
    const float* __restrict__ sc, const float* __restrict__ sh,
    __hip_bfloat16* __restrict__ C, int N, int K, int Dout) {
  __shared__ float Ast[32][68];
  __shared__ float Bs[32][64];
  const int tid = threadIdx.x;
  const int ty = tid >> 4, tx = tid & 15;
  const int brow = blockIdx.x * 64;
  const int bcol = blockIdx.y * 64;
  const int lm  = tid >> 3;
  const int lc4 = (tid & 7) * 4;
  const int bk  = tid >> 4;
  const int bc4 = (tid & 15) * 4;

  float acc[4][4] = {};

  for (int k0 = 0; k0 < K; k0 += 32) {
#pragma unroll
    for (int h = 0; h < 2; ++h) {
      int m = lm + h * 32;
      int row = brow + m;
      float4 v = make_float4(0.f, 0.f, 0.f, 0.f);
      if (row < N)
        v = *reinterpret_cast<const float4*>(&A[(size_t)row * K + k0 + lc4]);
      if (HAS_BN) {
        float t;
        t = v.x * sc[k0 + lc4 + 0] + sh[k0 + lc4 + 0]; v.x = t > 0.f ? t : 0.1f * t;
        t = v.y * sc[k0 + lc4 + 1] + sh[k0 + lc4 + 1]; v.y = t > 0.f ? t : 0.1f * t;
        t = v.z * sc[k0 + lc4 + 2] + sh[k0 + lc4 + 2]; v.z = t > 0.f ? t : 0.1f * t;
        t = v.w * sc[k0 + lc4 + 3] + sh[k0 + lc4 + 3]; v.w = t > 0.f ? t : 0.1f * t;
      }
      Ast[lc4 + 0][m] = v.x;
      Ast[lc4 + 1][m] = v.y;
      Ast[lc4 + 2][m] = v.z;
      Ast[lc4 + 3][m] = v.w;
    }
#pragma unroll
    for (int h = 0; h < 2; ++h) {
      int kk = bk + h * 16;
      *reinterpret_cast<float4*>(&Bs[kk][bc4]) =
          *reinterpret_cast<const float4*>(&W[(size_t)(k0 + kk) * Dout + bcol + bc4]);
    }
    __syncthreads();
#pragma unroll
    for (int kk = 0; kk < 32; ++kk) {
      float4 a4 = *reinterpret_cast<const float4*>(&Ast[kk][ty * 4]);
      float4 b4 = *reinterpret_cast<const float4*>(&Bs[kk][tx * 4]);
      float av[4] = {a4.x, a4.y, a4.z, a4.w};
      float bv[4] = {b4.x, b4.y, b4.z, b4.w};
#pragma unroll
      for (int i = 0; i < 4; ++i)
#pragma unroll
        for (int j = 0; j < 4; ++j) acc[i][j] += av[i] * bv[j];
    }
    __syncthreads();
  }
#pragma unroll
  for (int i = 0; i < 4; ++i) {
    int row = brow + ty * 4 + i;
    if (row < N) {
      __hip_bfloat162 p0, p1;
      p0.x = __float2bfloat16(acc[i][0]); p0.y = __float2bfloat16(acc[i][1]);
      p1.x = __float2bfloat16(acc[i][2]); p1.y = __float2bfloat16(acc[i][3]);
      __hip_bfloat162* cp =
          reinterpret_cast<__hip_bfloat162*>(C + (size_t)row * Dout + bcol + tx * 4);
      cp[0] = p0; cp[1] = p1;
    }
  }
}

// ---------------------------------------------------------------------------
// aggregation D=128: one wave per node, lane owns channels (2l, 2l+1).
// t is bf16: one 4B bf16x2 gather per edge per lane (256B/wave).
// ---------------------------------------------------------------------------
__global__ __launch_bounds__(256) void k_agg128(
    const __hip_bfloat16* __restrict__ t, const int* __restrict__ row_ptr,
    const int* __restrict__ src_perm, const float* __restrict__ w_perm,
    const float* __restrict__ dis, const float* __restrict__ bias,
    float* __restrict__ out, int N) {
  int node = blockIdx.x * 4 + (threadIdx.x >> 6);
  int lane = threadIdx.x & 63;
  if (node >= N) return;
  const __hip_bfloat162* t2 = reinterpret_cast<const __hip_bfloat162*>(t);
  float d = dis[node];
  float self = d * d;
  __hip_bfloat162 sv = t2[(size_t)node * 64 + lane];
  float acc0 = __bfloat162float(sv.x) * self;
  float acc1 = __bfloat162float(sv.y) * self;
  int beg = row_ptr[node], end = row_ptr[node + 1];
  for (int e = beg; e < end; ++e) {
    int s = src_perm[e];
    float w = w_perm[e];
    __hip_bfloat162 v = t2[(size_t)s * 64 + lane];
    acc0 += w * __bfloat162float(v.x);
    acc1 += w * __bfloat162float(v.y);
  }
  const float2* bias2 = reinterpret_cast<const float2*>(bias);
  float2 b = bias2[lane];
  float2* out2 = reinterpret_cast<float2*>(out);
  out2[(size_t)node * 64 + lane] = make_float2(acc0 + b.x, acc1 + b.y);
}

// aggregation D=64 + bias + L2 row-normalize (final layer) -> d_out
__global__ __launch_bounds__(256) void k_agg64_norm(
    const __hip_bfloat16* __restrict__ t, const int* __restrict__ row_ptr,
    const int* __restrict__ src_perm, const float* __restrict__ w_perm,
    const float* __restrict__ dis, const float* __restrict__ b3,
    float* __restrict__ out, int N) {
  int node = blockIdx.x * 4 + (threadIdx.x >> 6);
  int lane = threadIdx.x & 63;
  if (node >= N) return;
  float d = dis[node];
  float acc = __bfloat162float(t[(size_t)node * 64 + lane]) * d * d;
  int beg = row_ptr[node], end = row_ptr[node + 1];
  for (int e = beg; e < end; ++e)
    acc += w_perm[e] * __bfloat162float(t[(size_t)src_perm[e] * 64 + lane]);
  acc += b3[lane];
  float sq = acc * acc;
#pragma unroll
  for (int off = 32; off; off >>= 1) sq += __shfl_xor(sq, off, 64);
  float nrm = sqrtf(sq);
  out[(size_t)node * 64 + lane] = acc / fmaxf(nrm, 1e-12f);
}

// BN stats: partial sums per channel
__global__ void k_bn_partial(const float* __restrict__ h, float* __restrict__ sums,
                             int N) {
  int c = threadIdx.x & 127;
  int half = threadIdx.x >> 7;
  float s = 0.f, q = 0.f;
  for (int r = blockIdx.x * 2 + half; r < N; r += gridDim.x * 2) {
    float v = h[(size_t)r * 128 + c];
    s += v; q += v * v;
  }
  atomicAdd(&sums[c], s);
  atomicAdd(&sums[128 + c], q);
}

__global__ void k_bn_final(const float* __restrict__ sums, const float* __restrict__ g,
                           const float* __restrict__ be, float* __restrict__ scsh,
                           int N) {
  int c = threadIdx.x;  // 128
  float inv_n = 1.0f / (float)N;
  float mu = sums[c] * inv_n;
  float var = sums[128 + c] * inv_n - mu * mu;
  float sc = g[c] * rsqrtf(var + 1e-5f);
  scsh[c] = sc;
  scsh[128 + c] = be[c] - mu * sc;
}

// ---------------------------------------------------------------------------

extern "C" void kernel_launch(void* const* d_in, const int* in_sizes, int n_in,
                              void* d_out, int out_size, void* d_ws, size_t ws_size,
                              hipStream_t stream) {
  const float* x  = (const float*)d_in[0];
  const int*   ei = (const int*)d_in[1];
  const float* ew = (const float*)d_in[2];
  const float* W1 = (const float*)d_in[3];
  const float* b1 = (const float*)d_in[4];
  const float* g1 = (const float*)d_in[5];
  const float* be1= (const float*)d_in[6];
  const float* W2 = (const float*)d_in[7];
  const float* b2 = (const float*)d_in[8];
  const float* g2 = (const float*)d_in[9];
  const float* be2= (const float*)d_in[10];
  const float* W3 = (const float*)d_in[11];
  const float* b3 = (const float*)d_in[12];

  const int N = in_sizes[0] / 128;   // 100000
  const int E = in_sizes[2];         // 1600000
  const int* src = ei;
  const int* dst = ei + E;

  char* p = (char*)d_ws;
  auto alloc = [&](size_t bytes) -> void* {
    void* r = (void*)p;
    p += (bytes + 255) & ~(size_t)255;
    return r;
  };
  float* deg      = (float*)alloc((size_t)N * 4);
  float* dis      = (float*)alloc((size_t)N * 4);
  int*   count    = (int*)alloc((size_t)N * 4);
  int*   row_ptr  = (int*)alloc((size_t)(N + 1) * 4);
  int*   cursor   = (int*)alloc((size_t)N * 4);
  int*   part     = (int*)alloc(256 * 4);
  int*   src_perm = (int*)alloc((size_t)E * 4);
  float* w_perm   = (float*)alloc((size_t)E * 4);
  __hip_bfloat16* t_buf = (__hip_bfloat16*)alloc((size_t)N * 128 * 2);
  float* h_buf    = (float*)alloc((size_t)N * 128 * 4);
  float* bnsum    = (float*)alloc(512 * 4);
  float* scsh1    = (float*)alloc(256 * 4);
  float* scsh2    = (float*)alloc(256 * 4);
  (void)ws_size; (void)n_in; (void)out_size;

  const int gN = (N + 255) / 256;
  const int gE = (E + 255) / 256;
  const int scanBlocks = (N + 1023) / 1024;   // 98
  const int rowBlocks = (N + 63) / 64;
  const int aggBlocks = (N + 3) / 4;

  // graph build
  k_init<<<gN, 256, 0, stream>>>(deg, count, bnsum, N);
  k_deg<<<gE, 256, 0, stream>>>(dst, ew, deg, count, E);
  k_dis<<<gN, 256, 0, stream>>>(deg, dis, N);
  k_scan_part<<<scanBlocks, 256, 0, stream>>>(count, part, N);
  k_scan_top<<<1, 256, 0, stream>>>(part, scanBlocks, row_ptr + N);
  k_scan_bot<<<scanBlocks, 256, 0, stream>>>(count, part, row_ptr, cursor, N);
  k_scatter<<<gE, 256, 0, stream>>>(src, dst, ew, dis, cursor, src_perm, w_perm, E);

  // layer 1
  k_gemm<false><<<dim3(rowBlocks, 2), 256, 0, stream>>>(x, W1, nullptr, nullptr,
                                                        t_buf, N, 128, 128);
  k_agg128<<<aggBlocks, 256, 0, stream>>>(t_buf, row_ptr, src_perm, w_perm, dis,
                                          b1, h_buf, N);
  k_bn_partial<<<512, 256, 0, stream>>>(h_buf, bnsum, N);
  k_bn_final<<<1, 128, 0, stream>>>(bnsum, g1, be1, scsh1, N);

  // layer 2
  k_gemm<true><<<dim3(rowBlocks, 2), 256, 0, stream>>>(h_buf, W2, scsh1, scsh1 + 128,
                                                       t_buf, N, 128, 128);
  k_agg128<<<aggBlocks, 256, 0, stream>>>(t_buf, row_ptr, src_perm, w_perm, dis,
                                          b2, h_buf, N);
  k_bn_partial<<<512, 256, 0, stream>>>(h_buf, bnsum + 256, N);
  k_bn_final<<<1, 128, 0, stream>>>(bnsum + 256, g2, be2, scsh2, N);

  // layer 3
  k_gemm<true><<<dim3(rowBlocks, 1), 256, 0, stream>>>(h_buf, W3, scsh2, scsh2 + 128,
                                                       t_buf, N, 128, 64);
  k_agg64_norm<<<aggBlocks, 256, 0, stream>>>(t_buf, row_ptr, src_perm, w_perm, dis,
                                              b3, (float*)d_out, N);
}

// Round 5
// 709.909 us; speedup vs baseline: 1.8248x; 1.4630x over previous
//
#include <hip/hip_runtime.h>
#include <hip/hip_bf16.h>

typedef unsigned short ushort_t;
typedef unsigned int uint_t;
typedef __attribute__((ext_vector_type(8))) short bf16x8;
typedef __attribute__((ext_vector_type(4))) float f32x4;

// ---- bf16 bit helpers ------------------------------------------------------
__device__ __forceinline__ ushort_t f2bf(float f) {
  union { float f; uint_t u; } v; v.f = f;
  uint_t r = v.u + 0x7fffu + ((v.u >> 16) & 1u);   // RNE
  return (ushort_t)(r >> 16);
}
__device__ __forceinline__ float bf2f(ushort_t h) {
  union { uint_t u; float f; } v; v.u = ((uint_t)h) << 16;
  return v.f;
}
__device__ __forceinline__ float bflo(uint_t p) {   // low bf16 of packed pair
  union { uint_t u; float f; } v; v.u = p << 16;
  return v.f;
}
__device__ __forceinline__ float bfhi(uint_t p) {   // high bf16 of packed pair
  union { uint_t u; float f; } v; v.u = p & 0xffff0000u;
  return v.f;
}

// ---------------------------------------------------------------------------
// graph build: CSR by dst, premultiplied weights
// ---------------------------------------------------------------------------
__global__ void k_init(int* __restrict__ count, float* __restrict__ bnsum, int n) {
  int i = blockIdx.x * 256 + threadIdx.x;
  if (i < n) count[i] = 0;
  if (i < 512) bnsum[i] = 0.0f;
}

__global__ void k_count(const int* __restrict__ dst, int* __restrict__ count, int E) {
  int e = blockIdx.x * 256 + threadIdx.x;
  if (e < E) atomicAdd(&count[dst[e]], 1);
}

// hierarchical scan: count[N] -> row_ptr[N+1], cursor[N]
__global__ __launch_bounds__(256) void k_scan_part(const int* __restrict__ count,
                                                   int* __restrict__ part, int N) {
  int base = blockIdx.x * 1024;
  int t = threadIdx.x;
  int s = 0;
  for (int j = base + t; j < min(base + 1024, N); j += 256) s += count[j];
#pragma unroll
  for (int off = 32; off; off >>= 1) s += __shfl_xor(s, off, 64);
  __shared__ int ws[4];
  if ((t & 63) == 0) ws[t >> 6] = s;
  __syncthreads();
  if (t == 0) part[blockIdx.x] = ws[0] + ws[1] + ws[2] + ws[3];
}

__global__ __launch_bounds__(256) void k_scan_top(int* __restrict__ part, int nb,
                                                  int* __restrict__ total) {
  __shared__ int ls[256];
  int t = threadIdx.x;
  int v = (t < nb) ? part[t] : 0;
  ls[t] = v;
  __syncthreads();
  for (int off = 1; off < 256; off <<= 1) {
    int u = (t >= off) ? ls[t - off] : 0;
    __syncthreads();
    ls[t] += u;
    __syncthreads();
  }
  if (t < nb) part[t] = ls[t] - v;
  if (t == nb - 1) *total = ls[t];
}

__global__ __launch_bounds__(256) void k_scan_bot(const int* __restrict__ count,
                                                  const int* __restrict__ part,
                                                  int* __restrict__ row_ptr,
                                                  int* __restrict__ cursor, int N) {
  __shared__ int ls[256];
  int t = threadIdx.x;
  int idx = blockIdx.x * 1024 + t * 4;
  int c[4];
  int s = 0;
#pragma unroll
  for (int i = 0; i < 4; ++i) {
    int j = idx + i;
    c[i] = (j < N) ? count[j] : 0;
    s += c[i];
  }
  ls[t] = s;
  __syncthreads();
  for (int off = 1; off < 256; off <<= 1) {
    int u = (t >= off) ? ls[t - off] : 0;
    __syncthreads();
    ls[t] += u;
    __syncthreads();
  }
  int run = part[blockIdx.x] + ls[t] - s;
#pragma unroll
  for (int i = 0; i < 4; ++i) {
    int j = idx + i;
    if (j < N) { row_ptr[j] = run; cursor[j] = run; run += c[i]; }
  }
}

// scatter RAW edge weight (normalization applied later, saves one atomic pass)
__global__ void k_scatter(const int* __restrict__ src, const int* __restrict__ dst,
                          const float* __restrict__ ew, int* __restrict__ cursor,
                          int* __restrict__ src_perm, float* __restrict__ w_perm,
                          int E) {
  int e = blockIdx.x * 256 + threadIdx.x;
  if (e < E) {
    int d = dst[e];
    int pos = atomicAdd(&cursor[d], 1);
    src_perm[pos] = src[e];
    w_perm[pos] = ew[e];
  }
}

// deg[n] = 1 + sum(raw w in bucket); dis = rsqrt
__global__ void k_degdis(const float* __restrict__ w_perm,
                         const int* __restrict__ row_ptr,
                         float* __restrict__ dis, int N) {
  int n = blockIdx.x * 256 + threadIdx.x;
  if (n >= N) return;
  int beg = row_ptr[n], end = row_ptr[n + 1];
  float s = 1.0f;
  for (int e = beg; e < end; ++e) s += w_perm[e];
  dis[n] = rsqrtf(s);
}

// w_perm[e] = raw * dis[src] * dis[dst]
__global__ void k_normw(const int* __restrict__ src_perm,
                        const int* __restrict__ row_ptr,
                        const float* __restrict__ dis,
                        float* __restrict__ w_perm, int N) {
  int n = blockIdx.x * 256 + threadIdx.x;
  if (n >= N) return;
  int beg = row_ptr[n], end = row_ptr[n + 1];
  float dn = dis[n];
  for (int e = beg; e < end; ++e)
    w_perm[e] = w_perm[e] * dis[src_perm[e]] * dn;
}

// ---------------------------------------------------------------------------
// prep: f32 activations -> (optional BN+leaky) -> bf16 hi/lo split buffers
// ---------------------------------------------------------------------------
template <bool HAS_BN>
__global__ __launch_bounds__(256) void k_prep(const float* __restrict__ in,
                                              const float* __restrict__ scsh,
                                              ushort_t* __restrict__ ah,
                                              ushort_t* __restrict__ al, int n4) {
  int i = blockIdx.x * 256 + threadIdx.x;
  if (i >= n4) return;
  float4 v = reinterpret_cast<const float4*>(in)[i];
  if (HAS_BN) {
    int c = (i & 31) * 4;   // channel of first element (row length 128)
    float t;
    t = v.x * scsh[c + 0] + scsh[128 + c + 0]; v.x = t > 0.f ? t : 0.1f * t;
    t = v.y * scsh[c + 1] + scsh[128 + c + 1]; v.y = t > 0.f ? t : 0.1f * t;
    t = v.z * scsh[c + 2] + scsh[128 + c + 2]; v.z = t > 0.f ? t : 0.1f * t;
    t = v.w * scsh[c + 3] + scsh[128 + c + 3]; v.w = t > 0.f ? t : 0.1f * t;
  }
  ushort4 h, l;
  h.x = f2bf(v.x); l.x = f2bf(v.x - bf2f(h.x));
  h.y = f2bf(v.y); l.y = f2bf(v.y - bf2f(h.y));
  h.z = f2bf(v.z); l.z = f2bf(v.z - bf2f(h.z));
  h.w = f2bf(v.w); l.w = f2bf(v.w - bf2f(h.w));
  reinterpret_cast<ushort4*>(ah)[i] = h;
  reinterpret_cast<ushort4*>(al)[i] = l;
}

// W[K=128][D] f32 -> transposed bf16 hi/lo [D][128]
__global__ void k_prepw(const float* __restrict__ W, ushort_t* __restrict__ wth,
                        ushort_t* __restrict__ wtl, int D, int total) {
  int idx = blockIdx.x * 256 + threadIdx.x;
  if (idx >= total) return;
  int k = idx / D, d = idx - k * D;
  float f = W[idx];
  ushort_t h = f2bf(f);
  wth[d * 128 + k] = h;
  wtl[d * 128 + k] = f2bf(f - bf2f(h));
}

// ---------------------------------------------------------------------------
// MFMA GEMM: C[N][DOUT](bf16) = A[N][128] @ Wt[DOUT][128]^T with 2-term
// bf16 split: Ah*Wh + Al*Wh + Ah*Wl (near-f32 accuracy).
// block = 4 waves, each wave: 16 rows x DOUT cols, K=128.
// ---------------------------------------------------------------------------
template <int DOUT>
__global__ __launch_bounds__(256) void k_gemm_mfma(
    const ushort_t* __restrict__ Ah, const ushort_t* __restrict__ Al,
    const ushort_t* __restrict__ Wh, const ushort_t* __restrict__ Wl,
    ushort_t* __restrict__ C, int N) {
  // rows padded to 136 ushorts (272B): 16B-aligned chunks, banks spread 4/row
  __shared__ __attribute__((aligned(16))) ushort_t WHs[DOUT][136];
  __shared__ __attribute__((aligned(16))) ushort_t WLs[DOUT][136];
  const int tid = threadIdx.x;
  constexpr int CH = DOUT * 16;          // 16B chunks to stage per buffer
  for (int c = tid; c < CH; c += 256) {
    int r = c >> 4, k8 = (c & 15) << 3;
    *reinterpret_cast<bf16x8*>(&WHs[r][k8]) =
        *reinterpret_cast<const bf16x8*>(&Wh[r * 128 + k8]);
    *reinterpret_cast<bf16x8*>(&WLs[r][k8]) =
        *reinterpret_cast<const bf16x8*>(&Wl[r * 128 + k8]);
  }
  const int wave = tid >> 6, lane = tid & 63;
  const int col = lane & 15, g = lane >> 4;
  const int brow = blockIdx.x * 64 + wave * 16;
  // A fragments: row = brow + (lane&15), 16B per kstep
  const int arow = min(brow + col, N - 1);
  const size_t abase = (size_t)arow * 128 + g * 8;
  bf16x8 ah[4], al[4];
#pragma unroll
  for (int ks = 0; ks < 4; ++ks) {
    ah[ks] = *reinterpret_cast<const bf16x8*>(Ah + abase + ks * 32);
    al[ks] = *reinterpret_cast<const bf16x8*>(Al + abase + ks * 32);
  }
  __syncthreads();

  f32x4 acc[DOUT / 16];
#pragma unroll
  for (int ct = 0; ct < DOUT / 16; ++ct) acc[ct] = f32x4{0.f, 0.f, 0.f, 0.f};

#pragma unroll
  for (int ks = 0; ks < 4; ++ks) {
#pragma unroll
    for (int ct = 0; ct < DOUT / 16; ++ct) {
      int r = ct * 16 + col;
      bf16x8 bh = *reinterpret_cast<const bf16x8*>(&WHs[r][ks * 32 + g * 8]);
      bf16x8 bl = *reinterpret_cast<const bf16x8*>(&WLs[r][ks * 32 + g * 8]);
      acc[ct] = __builtin_amdgcn_mfma_f32_16x16x32_bf16(ah[ks], bh, acc[ct], 0, 0, 0);
      acc[ct] = __builtin_amdgcn_mfma_f32_16x16x32_bf16(al[ks], bh, acc[ct], 0, 0, 0);
      acc[ct] = __builtin_amdgcn_mfma_f32_16x16x32_bf16(ah[ks], bl, acc[ct], 0, 0, 0);
    }
  }
  // D layout: row = g*4 + r, col = ct*16 + (lane&15)
#pragma unroll
  for (int r = 0; r < 4; ++r) {
    int orow = brow + g * 4 + r;
    if (orow < N) {
#pragma unroll
      for (int ct = 0; ct < DOUT / 16; ++ct)
        C[(size_t)orow * DOUT + ct * 16 + col] = f2bf(acc[ct][r]);
    }
  }
}

// ---------------------------------------------------------------------------
// aggregation D=128: one wave/node, lane owns packed channels (2l,2l+1).
// 4-way MLP unroll; wave-uniform index/weight loads scalarized.
// ---------------------------------------------------------------------------
__global__ __launch_bounds__(256) void k_agg128(
    const ushort_t* __restrict__ t, const int* __restrict__ row_ptr,
    const int* __restrict__ src_perm, const float* __restrict__ w_perm,
    const float* __restrict__ dis, const float* __restrict__ bias,
    float* __restrict__ out, int N) {
  int node = __builtin_amdgcn_readfirstlane(blockIdx.x * 4 + (threadIdx.x >> 6));
  int lane = threadIdx.x & 63;
  if (node >= N) return;
  const uint_t* t2 = reinterpret_cast<const uint_t*>(t);
  float d = dis[node];
  float self = d * d;
  uint_t sv = t2[(size_t)node * 64 + lane];
  float acc0 = bflo(sv) * self;
  float acc1 = bfhi(sv) * self;
  int beg = row_ptr[node], end = row_ptr[node + 1];
  float x0 = 0.f, y0 = 0.f, x1 = 0.f, y1 = 0.f;
  float x2 = 0.f, y2 = 0.f, x3 = 0.f, y3 = 0.f;
  int e = beg;
  for (; e + 4 <= end; e += 4) {
    int s0 = src_perm[e], s1 = src_perm[e + 1];
    int s2 = src_perm[e + 2], s3 = src_perm[e + 3];
    float w0 = w_perm[e], w1 = w_perm[e + 1];
    float w2 = w_perm[e + 2], w3 = w_perm[e + 3];
    uint_t v0 = t2[(size_t)s0 * 64 + lane];
    uint_t v1 = t2[(size_t)s1 * 64 + lane];
    uint_t v2 = t2[(size_t)s2 * 64 + lane];
    uint_t v3 = t2[(size_t)s3 * 64 + lane];
    x0 += w0 * bflo(v0); y0 += w0 * bfhi(v0);
    x1 += w1 * bflo(v1); y1 += w1 * bfhi(v1);
    x2 += w2 * bflo(v2); y2 += w2 * bfhi(v2);
    x3 += w3 * bflo(v3); y3 += w3 * bfhi(v3);
  }
  for (; e < end; ++e) {
    int s = src_perm[e];
    float w = w_perm[e];
    uint_t v = t2[(size_t)s * 64 + lane];
    x0 += w * bflo(v); y0 += w * bfhi(v);
  }
  acc0 += (x0 + x1) + (x2 + x3);
  acc1 += (y0 + y1) + (y2 + y3);
  float2 b = reinterpret_cast<const float2*>(bias)[lane];
  reinterpret_cast<float2*>(out)[(size_t)node * 64 + lane] =
      make_float2(acc0 + b.x, acc1 + b.y);
}

// aggregation D=64 + bias + L2 row-normalize -> d_out
__global__ __launch_bounds__(256) void k_agg64_norm(
    const ushort_t* __restrict__ t, const int* __restrict__ row_ptr,
    const int* __restrict__ src_perm, const float* __restrict__ w_perm,
    const float* __restrict__ dis, const float* __restrict__ b3,
    float* __restrict__ out, int N) {
  int node = __builtin_amdgcn_readfirstlane(blockIdx.x * 4 + (threadIdx.x >> 6));
  int lane = threadIdx.x & 63;
  if (node >= N) return;
  float d = dis[node];
  float acc = bf2f(t[(size_t)node * 64 + lane]) * d * d;
  int beg = row_ptr[node], end = row_ptr[node + 1];
  float x0 = 0.f, x1 = 0.f, x2 = 0.f, x3 = 0.f;
  int e = beg;
  for (; e + 4 <= end; e += 4) {
    int s0 = src_perm[e], s1 = src_perm[e + 1];
    int s2 = src_perm[e + 2], s3 = src_perm[e + 3];
    float w0 = w_perm[e], w1 = w_perm[e + 1];
    float w2 = w_perm[e + 2], w3 = w_perm[e + 3];
    x0 += w0 * bf2f(t[(size_t)s0 * 64 + lane]);
    x1 += w1 * bf2f(t[(size_t)s1 * 64 + lane]);
    x2 += w2 * bf2f(t[(size_t)s2 * 64 + lane]);
    x3 += w3 * bf2f(t[(size_t)s3 * 64 + lane]);
  }
  for (; e < end; ++e)
    x0 += w_perm[e] * bf2f(t[(size_t)src_perm[e] * 64 + lane]);
  acc += (x0 + x1) + (x2 + x3);
  acc += b3[lane];
  float sq = acc * acc;
#pragma unroll
  for (int off = 32; off; off >>= 1) sq += __shfl_xor(sq, off, 64);
  float nrm = sqrtf(sq);
  out[(size_t)node * 64 + lane] = acc / fmaxf(nrm, 1e-12f);
}

// BN stats
__global__ void k_bn_partial(const float* __restrict__ h, float* __restrict__ sums,
                             int N) {
  int c = threadIdx.x & 127;
  int half = threadIdx.x >> 7;
  float s = 0.f, q = 0.f;
  for (int r = blockIdx.x * 2 + half; r < N; r += gridDim.x * 2) {
    float v = h[(size_t)r * 128 + c];
    s += v; q += v * v;
  }
  atomicAdd(&sums[c], s);
  atomicAdd(&sums[128 + c], q);
}

__global__ void k_bn_final(const float* __restrict__ sums, const float* __restrict__ g,
                           const float* __restrict__ be, float* __restrict__ scsh,
                           int N) {
  int c = threadIdx.x;  // 128
  float inv_n = 1.0f / (float)N;
  float mu = sums[c] * inv_n;
  float var = sums[128 + c] * inv_n - mu * mu;
  float sc = g[c] * rsqrtf(var + 1e-5f);
  scsh[c] = sc;
  scsh[128 + c] = be[c] - mu * sc;
}

// ---------------------------------------------------------------------------

extern "C" void kernel_launch(void* const* d_in, const int* in_sizes, int n_in,
                              void* d_out, int out_size, void* d_ws, size_t ws_size,
                              hipStream_t stream) {
  const float* x  = (const float*)d_in[0];
  const int*   ei = (const int*)d_in[1];
  const float* ew = (const float*)d_in[2];
  const float* W1 = (const float*)d_in[3];
  const float* b1 = (const float*)d_in[4];
  const float* g1 = (const float*)d_in[5];
  const float* be1= (const float*)d_in[6];
  const float* W2 = (const float*)d_in[7];
  const float* b2 = (const float*)d_in[8];
  const float* g2 = (const float*)d_in[9];
  const float* be2= (const float*)d_in[10];
  const float* W3 = (const float*)d_in[11];
  const float* b3 = (const float*)d_in[12];

  const int N = in_sizes[0] / 128;   // 100000
  const int E = in_sizes[2];         // 1600000
  const int* src = ei;
  const int* dst = ei + E;

  char* p = (char*)d_ws;
  auto alloc = [&](size_t bytes) -> void* {
    void* r = (void*)p;
    p += (bytes + 255) & ~(size_t)255;
    return r;
  };
  int*   count    = (int*)alloc((size_t)N * 4);
  int*   row_ptr  = (int*)alloc((size_t)(N + 1) * 4);
  int*   cursor   = (int*)alloc((size_t)N * 4);
  int*   part     = (int*)alloc(256 * 4);
  float* dis      = (float*)alloc((size_t)N * 4);
  int*   src_perm = (int*)alloc((size_t)E * 4);
  float* w_perm   = (float*)alloc((size_t)E * 4);
  ushort_t* ah    = (ushort_t*)alloc((size_t)N * 128 * 2 + 16384);
  ushort_t* al    = (ushort_t*)alloc((size_t)N * 128 * 2 + 16384);
  ushort_t* t_buf = (ushort_t*)alloc((size_t)N * 128 * 2);
  float* h_buf    = (float*)alloc((size_t)N * 128 * 4);
  ushort_t* w1th  = (ushort_t*)alloc(128 * 128 * 2);
  ushort_t* w1tl  = (ushort_t*)alloc(128 * 128 * 2);
  ushort_t* w2th  = (ushort_t*)alloc(128 * 128 * 2);
  ushort_t* w2tl  = (ushort_t*)alloc(128 * 128 * 2);
  ushort_t* w3th  = (ushort_t*)alloc(128 * 64 * 2);
  ushort_t* w3tl  = (ushort_t*)alloc(128 * 64 * 2);
  float* bnsum    = (float*)alloc(512 * 4);
  float* scsh1    = (float*)alloc(256 * 4);
  float* scsh2    = (float*)alloc(256 * 4);
  (void)ws_size; (void)n_in; (void)out_size;

  const int gN = (N + 255) / 256;
  const int gE = (E + 255) / 256;
  const int scanBlocks = (N + 1023) / 1024;
  const int gemmBlocks = (N + 63) / 64;
  const int aggBlocks = (N + 3) / 4;
  const int prepBlocks = (N * 32 + 255) / 256;

  // graph build
  k_init<<<gN, 256, 0, stream>>>(count, bnsum, N);
  k_count<<<gE, 256, 0, stream>>>(dst, count, E);
  k_scan_part<<<scanBlocks, 256, 0, stream>>>(count, part, N);
  k_scan_top<<<1, 256, 0, stream>>>(part, scanBlocks, row_ptr + N);
  k_scan_bot<<<scanBlocks, 256, 0, stream>>>(count, part, row_ptr, cursor, N);
  k_scatter<<<gE, 256, 0, stream>>>(src, dst, ew, cursor, src_perm, w_perm, E);
  k_degdis<<<gN, 256, 0, stream>>>(w_perm, row_ptr, dis, N);
  k_normw<<<gN, 256, 0, stream>>>(src_perm, row_ptr, dis, w_perm, N);

  // weight prep (tiny)
  k_prepw<<<64, 256, 0, stream>>>(W1, w1th, w1tl, 128, 128 * 128);
  k_prepw<<<64, 256, 0, stream>>>(W2, w2th, w2tl, 128, 128 * 128);
  k_prepw<<<32, 256, 0, stream>>>(W3, w3th, w3tl, 64, 128 * 64);

  // layer 1
  k_prep<false><<<prepBlocks, 256, 0, stream>>>(x, nullptr, ah, al, N * 32);
  k_gemm_mfma<128><<<gemmBlocks, 256, 0, stream>>>(ah, al, w1th, w1tl, t_buf, N);
  k_agg128<<<aggBlocks, 256, 0, stream>>>(t_buf, row_ptr, src_perm, w_perm, dis,
                                          b1, h_buf, N);
  k_bn_partial<<<512, 256, 0, stream>>>(h_buf, bnsum, N);
  k_bn_final<<<1, 128, 0, stream>>>(bnsum, g1, be1, scsh1, N);

  // layer 2
  k_prep<true><<<prepBlocks, 256, 0, stream>>>(h_buf, scsh1, ah, al, N * 32);
  k_gemm_mfma<128><<<gemmBlocks, 256, 0, stream>>>(ah, al, w2th, w2tl, t_buf, N);
  k_agg128<<<aggBlocks, 256, 0, stream>>>(t_buf, row_ptr, src_perm, w_perm, dis,
                                          b2, h_buf, N);
  k_bn_partial<<<512, 256, 0, stream>>>(h_buf, bnsum + 256, N);
  k_bn_final<<<1, 128, 0, stream>>>(bnsum + 256, g2, be2, scsh2, N);

  // layer 3
  k_prep<true><<<prepBlocks, 256, 0, stream>>>(h_buf, scsh2, ah, al, N * 32);
  k_gemm_mfma<64><<<gemmBlocks, 256, 0, stream>>>(ah, al, w3th, w3tl, t_buf, N);
  k_agg64_norm<<<aggBlocks, 256, 0, stream>>>(t_buf, row_ptr, src_perm, w_perm, dis,
                                              b3, (float*)d_out, N);
}

// Round 6
// 706.802 us; speedup vs baseline: 1.8328x; 1.0044x over previous
//
#include <hip/hip_runtime.h>
#include <hip/hip_bf16.h>

typedef unsigned short ushort_t;
typedef unsigned int uint_t;
typedef __attribute__((ext_vector_type(8))) short bf16x8;
typedef __attribute__((ext_vector_type(4))) float f32x4;

// ---- bf16 bit helpers ------------------------------------------------------
__device__ __forceinline__ ushort_t f2bf(float f) {
  union { float f; uint_t u; } v; v.f = f;
  uint_t r = v.u + 0x7fffu + ((v.u >> 16) & 1u);   // RNE
  return (ushort_t)(r >> 16);
}
__device__ __forceinline__ float bf2f(ushort_t h) {
  union { uint_t u; float f; } v; v.u = ((uint_t)h) << 16;
  return v.f;
}
__device__ __forceinline__ float bflo(uint_t p) {
  union { uint_t u; float f; } v; v.u = p << 16;
  return v.f;
}
__device__ __forceinline__ float bfhi(uint_t p) {
  union { uint_t u; float f; } v; v.u = p & 0xffff0000u;
  return v.f;
}

// ---------------------------------------------------------------------------
// graph build: CSR by dst with premultiplied weights, packed {src,w} records
// ---------------------------------------------------------------------------
__global__ void k_init(float* __restrict__ deg, int* __restrict__ count,
                       float* __restrict__ bnsum, int n) {
  int i = blockIdx.x * 256 + threadIdx.x;
  if (i < n) { deg[i] = 1.0f; count[i] = 0; }   // deg starts at 1 (self-loop)
  if (i < 512) bnsum[i] = 0.0f;
}

// one pass: weighted degree + bucket count
__global__ void k_deg(const int* __restrict__ dst, const float* __restrict__ ew,
                      float* __restrict__ deg, int* __restrict__ count, int E) {
  int e = blockIdx.x * 256 + threadIdx.x;
  if (e < E) {
    int d = dst[e];
    atomicAdd(&deg[d], ew[e]);
    atomicAdd(&count[d], 1);
  }
}

__global__ void k_dis(const float* __restrict__ deg, float* __restrict__ dis, int n) {
  int i = blockIdx.x * 256 + threadIdx.x;
  if (i < n) dis[i] = rsqrtf(deg[i]);   // deg >= 1
}

// hierarchical scan: count[N] -> row_ptr[N+1], cursor[N]
__global__ __launch_bounds__(256) void k_scan_part(const int* __restrict__ count,
                                                   int* __restrict__ part, int N) {
  int base = blockIdx.x * 1024;
  int t = threadIdx.x;
  int s = 0;
  for (int j = base + t; j < min(base + 1024, N); j += 256) s += count[j];
#pragma unroll
  for (int off = 32; off; off >>= 1) s += __shfl_xor(s, off, 64);
  __shared__ int ws[4];
  if ((t & 63) == 0) ws[t >> 6] = s;
  __syncthreads();
  if (t == 0) part[blockIdx.x] = ws[0] + ws[1] + ws[2] + ws[3];
}

__global__ __launch_bounds__(256) void k_scan_top(int* __restrict__ part, int nb,
                                                  int* __restrict__ total) {
  __shared__ int ls[256];
  int t = threadIdx.x;
  int v = (t < nb) ? part[t] : 0;
  ls[t] = v;
  __syncthreads();
  for (int off = 1; off < 256; off <<= 1) {
    int u = (t >= off) ? ls[t - off] : 0;
    __syncthreads();
    ls[t] += u;
    __syncthreads();
  }
  if (t < nb) part[t] = ls[t] - v;
  if (t == nb - 1) *total = ls[t];
}

__global__ __launch_bounds__(256) void k_scan_bot(const int* __restrict__ count,
                                                  const int* __restrict__ part,
                                                  int* __restrict__ row_ptr,
                                                  int* __restrict__ cursor, int N) {
  __shared__ int ls[256];
  int t = threadIdx.x;
  int idx = blockIdx.x * 1024 + t * 4;
  int c[4];
  int s = 0;
#pragma unroll
  for (int i = 0; i < 4; ++i) {
    int j = idx + i;
    c[i] = (j < N) ? count[j] : 0;
    s += c[i];
  }
  ls[t] = s;
  __syncthreads();
  for (int off = 1; off < 256; off <<= 1) {
    int u = (t >= off) ? ls[t - off] : 0;
    __syncthreads();
    ls[t] += u;
    __syncthreads();
  }
  int run = part[blockIdx.x] + ls[t] - s;
#pragma unroll
  for (int i = 0; i < 4; ++i) {
    int j = idx + i;
    if (j < N) { row_ptr[j] = run; cursor[j] = run; run += c[i]; }
  }
}

// scatter packed {src, premultiplied w}: ONE 8B store per edge (one cache
// line instead of two -> halves write-allocate traffic vs split arrays)
__global__ void k_scatter(const int* __restrict__ src, const int* __restrict__ dst,
                          const float* __restrict__ ew, const float* __restrict__ dis,
                          int* __restrict__ cursor, int2* __restrict__ pk, int E) {
  int e = blockIdx.x * 256 + threadIdx.x;
  if (e < E) {
    int s = src[e], d = dst[e];
    int pos = atomicAdd(&cursor[d], 1);
    float w = ew[e] * dis[s] * dis[d];
    pk[pos] = make_int2(s, __float_as_int(w));
  }
}

// W[K=128][D] f32 -> transposed bf16 hi/lo [D][128]
__global__ void k_prepw(const float* __restrict__ W, ushort_t* __restrict__ wth,
                        ushort_t* __restrict__ wtl, int D, int total) {
  int idx = blockIdx.x * 256 + threadIdx.x;
  if (idx >= total) return;
  int k = idx / D, d = idx - k * D;
  float f = W[idx];
  ushort_t h = f2bf(f);
  wth[d * 128 + k] = h;
  wtl[d * 128 + k] = f2bf(f - bf2f(h));
}

// ---------------------------------------------------------------------------
// MFMA GEMM: C[N][DOUT](bf16) = act(A[N][128]) @ Wt[DOUT][128]^T.
// A read as f32; BN+leaky + hi/lo bf16 split done IN-REGISTER (no prep pass).
// 2-term split: Ah*Wh + Al*Wh + Ah*Wl (near-f32 accuracy).
// block = 4 waves, each wave: 16 rows x DOUT cols, K=128.
// ---------------------------------------------------------------------------
template <int DOUT, bool HAS_BN>
__global__ __launch_bounds__(256) void k_gemm_mfma(
    const float* __restrict__ A, const float* __restrict__ scsh,
    const ushort_t* __restrict__ Wh, const ushort_t* __restrict__ Wl,
    ushort_t* __restrict__ C, int N) {
  __shared__ __attribute__((aligned(16))) ushort_t WHs[DOUT][136];
  __shared__ __attribute__((aligned(16))) ushort_t WLs[DOUT][136];
  const int tid = threadIdx.x;
  constexpr int CH = DOUT * 16;
  for (int c = tid; c < CH; c += 256) {
    int r = c >> 4, k8 = (c & 15) << 3;
    *reinterpret_cast<bf16x8*>(&WHs[r][k8]) =
        *reinterpret_cast<const bf16x8*>(&Wh[r * 128 + k8]);
    *reinterpret_cast<bf16x8*>(&WLs[r][k8]) =
        *reinterpret_cast<const bf16x8*>(&Wl[r * 128 + k8]);
  }
  const int wave = tid >> 6, lane = tid & 63;
  const int col = lane & 15, g = lane >> 4;
  const int brow = blockIdx.x * 64 + wave * 16;
  const int arow = min(brow + col, N - 1);
  const float* ap = A + (size_t)arow * 128;
  bf16x8 ah[4], al[4];
#pragma unroll
  for (int ks = 0; ks < 4; ++ks) {
    const int c0 = ks * 32 + g * 8;
    float4 u = *reinterpret_cast<const float4*>(ap + c0);
    float4 v = *reinterpret_cast<const float4*>(ap + c0 + 4);
    float vals[8] = {u.x, u.y, u.z, u.w, v.x, v.y, v.z, v.w};
    if (HAS_BN) {
      float4 s0 = *reinterpret_cast<const float4*>(scsh + c0);
      float4 s1 = *reinterpret_cast<const float4*>(scsh + c0 + 4);
      float4 h0 = *reinterpret_cast<const float4*>(scsh + 128 + c0);
      float4 h1 = *reinterpret_cast<const float4*>(scsh + 128 + c0 + 4);
      float scl[8] = {s0.x, s0.y, s0.z, s0.w, s1.x, s1.y, s1.z, s1.w};
      float shf[8] = {h0.x, h0.y, h0.z, h0.w, h1.x, h1.y, h1.z, h1.w};
#pragma unroll
      for (int j = 0; j < 8; ++j) {
        float t = vals[j] * scl[j] + shf[j];
        vals[j] = t > 0.f ? t : 0.1f * t;
      }
    }
#pragma unroll
    for (int j = 0; j < 8; ++j) {
      ushort_t hh = f2bf(vals[j]);
      ah[ks][j] = (short)hh;
      al[ks][j] = (short)f2bf(vals[j] - bf2f(hh));
    }
  }
  __syncthreads();

  f32x4 acc[DOUT / 16];
#pragma unroll
  for (int ct = 0; ct < DOUT / 16; ++ct) acc[ct] = f32x4{0.f, 0.f, 0.f, 0.f};

#pragma unroll
  for (int ks = 0; ks < 4; ++ks) {
#pragma unroll
    for (int ct = 0; ct < DOUT / 16; ++ct) {
      int r = ct * 16 + col;
      bf16x8 bh = *reinterpret_cast<const bf16x8*>(&WHs[r][ks * 32 + g * 8]);
      bf16x8 bl = *reinterpret_cast<const bf16x8*>(&WLs[r][ks * 32 + g * 8]);
      acc[ct] = __builtin_amdgcn_mfma_f32_16x16x32_bf16(ah[ks], bh, acc[ct], 0, 0, 0);
      acc[ct] = __builtin_amdgcn_mfma_f32_16x16x32_bf16(al[ks], bh, acc[ct], 0, 0, 0);
      acc[ct] = __builtin_amdgcn_mfma_f32_16x16x32_bf16(ah[ks], bl, acc[ct], 0, 0, 0);
    }
  }
  // D layout: row = g*4 + r, col = ct*16 + (lane&15)
#pragma unroll
  for (int r = 0; r < 4; ++r) {
    int orow = brow + g * 4 + r;
    if (orow < N) {
#pragma unroll
      for (int ct = 0; ct < DOUT / 16; ++ct)
        C[(size_t)orow * DOUT + ct * 16 + col] = f2bf(acc[ct][r]);
    }
  }
}

// ---------------------------------------------------------------------------
// aggregation D=128: one wave/node, lane owns packed channels (2l,2l+1).
// 4-way unroll, packed 8B edge records.
// ---------------------------------------------------------------------------
__global__ __launch_bounds__(256) void k_agg128(
    const ushort_t* __restrict__ t, const int* __restrict__ row_ptr,
    const int2* __restrict__ pk, const float* __restrict__ dis,
    const float* __restrict__ bias, float* __restrict__ out, int N) {
  int node = __builtin_amdgcn_readfirstlane(blockIdx.x * 4 + (threadIdx.x >> 6));
  int lane = threadIdx.x & 63;
  if (node >= N) return;
  const uint_t* t2 = reinterpret_cast<const uint_t*>(t);
  float d = dis[node];
  float self = d * d;
  uint_t sv = t2[(size_t)node * 64 + lane];
  float acc0 = bflo(sv) * self;
  float acc1 = bfhi(sv) * self;
  int beg = row_ptr[node], end = row_ptr[node + 1];
  float x0 = 0.f, y0 = 0.f, x1 = 0.f, y1 = 0.f;
  float x2 = 0.f, y2 = 0.f, x3 = 0.f, y3 = 0.f;
  int e = beg;
  for (; e + 4 <= end; e += 4) {
    int2 p0 = pk[e], p1 = pk[e + 1], p2 = pk[e + 2], p3 = pk[e + 3];
    float w0 = __int_as_float(p0.y), w1 = __int_as_float(p1.y);
    float w2 = __int_as_float(p2.y), w3 = __int_as_float(p3.y);
    uint_t v0 = t2[(size_t)p0.x * 64 + lane];
    uint_t v1 = t2[(size_t)p1.x * 64 + lane];
    uint_t v2 = t2[(size_t)p2.x * 64 + lane];
    uint_t v3 = t2[(size_t)p3.x * 64 + lane];
    x0 += w0 * bflo(v0); y0 += w0 * bfhi(v0);
    x1 += w1 * bflo(v1); y1 += w1 * bfhi(v1);
    x2 += w2 * bflo(v2); y2 += w2 * bfhi(v2);
    x3 += w3 * bflo(v3); y3 += w3 * bfhi(v3);
  }
  for (; e < end; ++e) {
    int2 p = pk[e];
    float w = __int_as_float(p.y);
    uint_t v = t2[(size_t)p.x * 64 + lane];
    x0 += w * bflo(v); y0 += w * bfhi(v);
  }
  acc0 += (x0 + x1) + (x2 + x3);
  acc1 += (y0 + y1) + (y2 + y3);
  float2 b = reinterpret_cast<const float2*>(bias)[lane];
  reinterpret_cast<float2*>(out)[(size_t)node * 64 + lane] =
      make_float2(acc0 + b.x, acc1 + b.y);
}

// aggregation D=64 + bias + L2 row-normalize -> d_out
__global__ __launch_bounds__(256) void k_agg64_norm(
    const ushort_t* __restrict__ t, const int* __restrict__ row_ptr,
    const int2* __restrict__ pk, const float* __restrict__ dis,
    const float* __restrict__ b3, float* __restrict__ out, int N) {
  int node = __builtin_amdgcn_readfirstlane(blockIdx.x * 4 + (threadIdx.x >> 6));
  int lane = threadIdx.x & 63;
  if (node >= N) return;
  float d = dis[node];
  float acc = bf2f(t[(size_t)node * 64 + lane]) * d * d;
  int beg = row_ptr[node], end = row_ptr[node + 1];
  float x0 = 0.f, x1 = 0.f, x2 = 0.f, x3 = 0.f;
  int e = beg;
  for (; e + 4 <= end; e += 4) {
    int2 p0 = pk[e], p1 = pk[e + 1], p2 = pk[e + 2], p3 = pk[e + 3];
    x0 += __int_as_float(p0.y) * bf2f(t[(size_t)p0.x * 64 + lane]);
    x1 += __int_as_float(p1.y) * bf2f(t[(size_t)p1.x * 64 + lane]);
    x2 += __int_as_float(p2.y) * bf2f(t[(size_t)p2.x * 64 + lane]);
    x3 += __int_as_float(p3.y) * bf2f(t[(size_t)p3.x * 64 + lane]);
  }
  for (; e < end; ++e) {
    int2 p = pk[e];
    x0 += __int_as_float(p.y) * bf2f(t[(size_t)p.x * 64 + lane]);
  }
  acc += (x0 + x1) + (x2 + x3);
  acc += b3[lane];
  float sq = acc * acc;
#pragma unroll
  for (int off = 32; off; off >>= 1) sq += __shfl_xor(sq, off, 64);
  float nrm = sqrtf(sq);
  out[(size_t)node * 64 + lane] = acc / fmaxf(nrm, 1e-12f);
}

// BN stats
__global__ void k_bn_partial(const float* __restrict__ h, float* __restrict__ sums,
                             int N) {
  int c = threadIdx.x & 127;
  int half = threadIdx.x >> 7;
  float s = 0.f, q = 0.f;
  for (int r = blockIdx.x * 2 + half; r < N; r += gridDim.x * 2) {
    float v = h[(size_t)r * 128 + c];
    s += v; q += v * v;
  }
  atomicAdd(&sums[c], s);
  atomicAdd(&sums[128 + c], q);
}

__global__ void k_bn_final(const float* __restrict__ sums, const float* __restrict__ g,
                           const float* __restrict__ be, float* __restrict__ scsh,
                           int N) {
  int c = threadIdx.x;  // 128
  float inv_n = 1.0f / (float)N;
  float mu = sums[c] * inv_n;
  float var = sums[128 + c] * inv_n - mu * mu;
  float sc = g[c] * rsqrtf(var + 1e-5f);
  scsh[c] = sc;
  scsh[128 + c] = be[c] - mu * sc;
}

// ---------------------------------------------------------------------------

extern "C" void kernel_launch(void* const* d_in, const int* in_sizes, int n_in,
                              void* d_out, int out_size, void* d_ws, size_t ws_size,
                              hipStream_t stream) {
  const float* x  = (const float*)d_in[0];
  const int*   ei = (const int*)d_in[1];
  const float* ew = (const float*)d_in[2];
  const float* W1 = (const float*)d_in[3];
  const float* b1 = (const float*)d_in[4];
  const float* g1 = (const float*)d_in[5];
  const float* be1= (const float*)d_in[6];
  const float* W2 = (const float*)d_in[7];
  const float* b2 = (const float*)d_in[8];
  const float* g2 = (const float*)d_in[9];
  const float* be2= (const float*)d_in[10];
  const float* W3 = (const float*)d_in[11];
  const float* b3 = (const float*)d_in[12];

  const int N = in_sizes[0] / 128;   // 100000
  const int E = in_sizes[2];         // 1600000
  const int* src = ei;
  const int* dst = ei + E;

  char* p = (char*)d_ws;
  auto alloc = [&](size_t bytes) -> void* {
    void* r = (void*)p;
    p += (bytes + 255) & ~(size_t)255;
    return r;
  };
  float* deg      = (float*)alloc((size_t)N * 4);
  float* dis      = (float*)alloc((size_t)N * 4);
  int*   count    = (int*)alloc((size_t)N * 4);
  int*   row_ptr  = (int*)alloc((size_t)(N + 1) * 4);
  int*   cursor   = (int*)alloc((size_t)N * 4);
  int*   part     = (int*)alloc(256 * 4);
  int2*  pk       = (int2*)alloc((size_t)E * 8);
  ushort_t* t_buf = (ushort_t*)alloc((size_t)N * 128 * 2);
  float* h_buf    = (float*)alloc((size_t)N * 128 * 4);
  ushort_t* w1th  = (ushort_t*)alloc(128 * 128 * 2);
  ushort_t* w1tl  = (ushort_t*)alloc(128 * 128 * 2);
  ushort_t* w2th  = (ushort_t*)alloc(128 * 128 * 2);
  ushort_t* w2tl  = (ushort_t*)alloc(128 * 128 * 2);
  ushort_t* w3th  = (ushort_t*)alloc(128 * 64 * 2);
  ushort_t* w3tl  = (ushort_t*)alloc(128 * 64 * 2);
  float* bnsum    = (float*)alloc(512 * 4);
  float* scsh1    = (float*)alloc(256 * 4);
  float* scsh2    = (float*)alloc(256 * 4);
  (void)ws_size; (void)n_in; (void)out_size;

  const int gN = (N + 255) / 256;
  const int gE = (E + 255) / 256;
  const int scanBlocks = (N + 1023) / 1024;
  const int gemmBlocks = (N + 63) / 64;
  const int aggBlocks = (N + 3) / 4;

  // graph build
  k_init<<<gN, 256, 0, stream>>>(deg, count, bnsum, N);
  k_deg<<<gE, 256, 0, stream>>>(dst, ew, deg, count, E);
  k_dis<<<gN, 256, 0, stream>>>(deg, dis, N);
  k_scan_part<<<scanBlocks, 256, 0, stream>>>(count, part, N);
  k_scan_top<<<1, 256, 0, stream>>>(part, scanBlocks, row_ptr + N);
  k_scan_bot<<<scanBlocks, 256, 0, stream>>>(count, part, row_ptr, cursor, N);
  k_scatter<<<gE, 256, 0, stream>>>(src, dst, ew, dis, cursor, pk, E);

  // weight prep (tiny)
  k_prepw<<<64, 256, 0, stream>>>(W1, w1th, w1tl, 128, 128 * 128);
  k_prepw<<<64, 256, 0, stream>>>(W2, w2th, w2tl, 128, 128 * 128);
  k_prepw<<<32, 256, 0, stream>>>(W3, w3th, w3tl, 64, 128 * 64);

  // layer 1 (no BN on input)
  k_gemm_mfma<128, false><<<gemmBlocks, 256, 0, stream>>>(x, nullptr, w1th, w1tl,
                                                          t_buf, N);
  k_agg128<<<aggBlocks, 256, 0, stream>>>(t_buf, row_ptr, pk, dis, b1, h_buf, N);
  k_bn_partial<<<512, 256, 0, stream>>>(h_buf, bnsum, N);
  k_bn_final<<<1, 128, 0, stream>>>(bnsum, g1, be1, scsh1, N);

  // layer 2 (BN1+leaky fused into GEMM A-load, in-register)
  k_gemm_mfma<128, true><<<gemmBlocks, 256, 0, stream>>>(h_buf, scsh1, w2th, w2tl,
                                                         t_buf, N);
  k_agg128<<<aggBlocks, 256, 0, stream>>>(t_buf, row_ptr, pk, dis, b2, h_buf, N);
  k_bn_partial<<<512, 256, 0, stream>>>(h_buf, bnsum + 256, N);
  k_bn_final<<<1, 128, 0, stream>>>(bnsum + 256, g2, be2, scsh2, N);

  // layer 3 (BN2+leaky fused, Dout=64, fused bias+L2 norm)
  k_gemm_mfma<64, true><<<gemmBlocks, 256, 0, stream>>>(h_buf, scsh2, w3th, w3tl,
                                                        t_buf, N);
  k_agg64_norm<<<aggBlocks, 256, 0, stream>>>(t_buf, row_ptr, pk, dis, b3,
                                              (float*)d_out, N);
}

// Round 7
// 607.872 us; speedup vs baseline: 2.1311x; 1.1627x over previous
//
#include <hip/hip_runtime.h>
#include <hip/hip_bf16.h>

typedef unsigned short ushort_t;
typedef unsigned int uint_t;
typedef __attribute__((ext_vector_type(8))) short bf16x8;
typedef __attribute__((ext_vector_type(4))) float f32x4;

// ---- bf16 bit helpers ------------------------------------------------------
__device__ __forceinline__ ushort_t f2bf(float f) {
  union { float f; uint_t u; } v; v.f = f;
  uint_t r = v.u + 0x7fffu + ((v.u >> 16) & 1u);   // RNE
  return (ushort_t)(r >> 16);
}
__device__ __forceinline__ float bf2f(ushort_t h) {
  union { uint_t u; float f; } v; v.u = ((uint_t)h) << 16;
  return v.f;
}
__device__ __forceinline__ float bflo(uint_t p) {
  union { uint_t u; float f; } v; v.u = p << 16;
  return v.f;
}
__device__ __forceinline__ float bfhi(uint_t p) {
  union { uint_t u; float f; } v; v.u = p & 0xffff0000u;
  return v.f;
}

// ---------------------------------------------------------------------------
// graph build: CSR by dst. ONE atomic per edge total (count+rank in one op),
// scatter is atomic-free via pos = row_ptr[dst] + rank.
// ---------------------------------------------------------------------------
__global__ void k_init(int* __restrict__ count, float* __restrict__ bnsum, int n) {
  int i = blockIdx.x * 256 + threadIdx.x;
  if (i < n) count[i] = 0;
  if (i < 512) bnsum[i] = 0.0f;
}

// count buckets; atomic return value = within-bucket rank (stored, reused)
__global__ void k_count_rank(const int* __restrict__ dst, int* __restrict__ count,
                             int* __restrict__ rank, int E) {
  int e = blockIdx.x * 256 + threadIdx.x;
  if (e < E) rank[e] = atomicAdd(&count[dst[e]], 1);
}

// hierarchical scan: count[N] -> row_ptr[N+1]
__global__ __launch_bounds__(256) void k_scan_part(const int* __restrict__ count,
                                                   int* __restrict__ part, int N) {
  int base = blockIdx.x * 1024;
  int t = threadIdx.x;
  int s = 0;
  for (int j = base + t; j < min(base + 1024, N); j += 256) s += count[j];
#pragma unroll
  for (int off = 32; off; off >>= 1) s += __shfl_xor(s, off, 64);
  __shared__ int ws[4];
  if ((t & 63) == 0) ws[t >> 6] = s;
  __syncthreads();
  if (t == 0) part[blockIdx.x] = ws[0] + ws[1] + ws[2] + ws[3];
}

__global__ __launch_bounds__(256) void k_scan_top(int* __restrict__ part, int nb,
                                                  int* __restrict__ total) {
  __shared__ int ls[256];
  int t = threadIdx.x;
  int v = (t < nb) ? part[t] : 0;
  ls[t] = v;
  __syncthreads();
  for (int off = 1; off < 256; off <<= 1) {
    int u = (t >= off) ? ls[t - off] : 0;
    __syncthreads();
    ls[t] += u;
    __syncthreads();
  }
  if (t < nb) part[t] = ls[t] - v;
  if (t == nb - 1) *total = ls[t];
}

__global__ __launch_bounds__(256) void k_scan_bot(const int* __restrict__ count,
                                                  const int* __restrict__ part,
                                                  int* __restrict__ row_ptr, int N) {
  __shared__ int ls[256];
  int t = threadIdx.x;
  int idx = blockIdx.x * 1024 + t * 4;
  int c[4];
  int s = 0;
#pragma unroll
  for (int i = 0; i < 4; ++i) {
    int j = idx + i;
    c[i] = (j < N) ? count[j] : 0;
    s += c[i];
  }
  ls[t] = s;
  __syncthreads();
  for (int off = 1; off < 256; off <<= 1) {
    int u = (t >= off) ? ls[t - off] : 0;
    __syncthreads();
    ls[t] += u;
    __syncthreads();
  }
  int run = part[blockIdx.x] + ls[t] - s;
#pragma unroll
  for (int i = 0; i < 4; ++i) {
    int j = idx + i;
    if (j < N) { row_ptr[j] = run; run += c[i]; }
  }
}

// atomic-free scatter: packed {src, raw ew}, one 8B store per edge
__global__ void k_scatter(const int* __restrict__ src, const int* __restrict__ dst,
                          const float* __restrict__ ew,
                          const int* __restrict__ row_ptr,
                          const int* __restrict__ rank, int2* __restrict__ pk,
                          int E) {
  int e = blockIdx.x * 256 + threadIdx.x;
  if (e < E) {
    int d = dst[e];
    int pos = row_ptr[d] + rank[e];
    pk[pos] = make_int2(src[e], __float_as_int(ew[e]));
  }
}

// CSR pass: deg[n] = 1 + sum(raw w); dis = rsqrt(deg)
__global__ void k_degdis(const int2* __restrict__ pk, const int* __restrict__ row_ptr,
                         float* __restrict__ dis, int N) {
  int n = blockIdx.x * 256 + threadIdx.x;
  if (n >= N) return;
  int beg = row_ptr[n], end = row_ptr[n + 1];
  float s = 1.0f;
  for (int e = beg; e < end; ++e) s += __int_as_float(pk[e].y);
  dis[n] = rsqrtf(s);
}

// CSR pass: w = raw * dis[src] * dis[dst] (in place in pk records)
__global__ void k_normw(int2* __restrict__ pk, const int* __restrict__ row_ptr,
                        const float* __restrict__ dis, int N) {
  int n = blockIdx.x * 256 + threadIdx.x;
  if (n >= N) return;
  int beg = row_ptr[n], end = row_ptr[n + 1];
  float dn = dis[n];
  for (int e = beg; e < end; ++e) {
    int2 p = pk[e];
    p.y = __float_as_int(__int_as_float(p.y) * dis[p.x] * dn);
    pk[e] = p;
  }
}

// W[K=128][D] f32 -> transposed bf16 hi/lo [D][128]
__global__ void k_prepw(const float* __restrict__ W, ushort_t* __restrict__ wth,
                        ushort_t* __restrict__ wtl, int D, int total) {
  int idx = blockIdx.x * 256 + threadIdx.x;
  if (idx >= total) return;
  int k = idx / D, d = idx - k * D;
  float f = W[idx];
  ushort_t h = f2bf(f);
  wth[d * 128 + k] = h;
  wtl[d * 128 + k] = f2bf(f - bf2f(h));
}

// ---------------------------------------------------------------------------
// MFMA GEMM: C[N][DOUT](bf16) = act(A[N][128]) @ Wt[DOUT][128]^T.
// BN+leaky + hi/lo bf16 split in-register; 2-term split (Ah*Wh+Al*Wh+Ah*Wl).
// ---------------------------------------------------------------------------
template <int DOUT, bool HAS_BN>
__global__ __launch_bounds__(256) void k_gemm_mfma(
    const float* __restrict__ A, const float* __restrict__ scsh,
    const ushort_t* __restrict__ Wh, const ushort_t* __restrict__ Wl,
    ushort_t* __restrict__ C, int N) {
  __shared__ __attribute__((aligned(16))) ushort_t WHs[DOUT][136];
  __shared__ __attribute__((aligned(16))) ushort_t WLs[DOUT][136];
  const int tid = threadIdx.x;
  constexpr int CH = DOUT * 16;
  for (int c = tid; c < CH; c += 256) {
    int r = c >> 4, k8 = (c & 15) << 3;
    *reinterpret_cast<bf16x8*>(&WHs[r][k8]) =
        *reinterpret_cast<const bf16x8*>(&Wh[r * 128 + k8]);
    *reinterpret_cast<bf16x8*>(&WLs[r][k8]) =
        *reinterpret_cast<const bf16x8*>(&Wl[r * 128 + k8]);
  }
  const int wave = tid >> 6, lane = tid & 63;
  const int col = lane & 15, g = lane >> 4;
  const int brow = blockIdx.x * 64 + wave * 16;
  const int arow = min(brow + col, N - 1);
  const float* ap = A + (size_t)arow * 128;
  bf16x8 ah[4], al[4];
#pragma unroll
  for (int ks = 0; ks < 4; ++ks) {
    const int c0 = ks * 32 + g * 8;
    float4 u = *reinterpret_cast<const float4*>(ap + c0);
    float4 v = *reinterpret_cast<const float4*>(ap + c0 + 4);
    float vals[8] = {u.x, u.y, u.z, u.w, v.x, v.y, v.z, v.w};
    if (HAS_BN) {
      float4 s0 = *reinterpret_cast<const float4*>(scsh + c0);
      float4 s1 = *reinterpret_cast<const float4*>(scsh + c0 + 4);
      float4 h0 = *reinterpret_cast<const float4*>(scsh + 128 + c0);
      float4 h1 = *reinterpret_cast<const float4*>(scsh + 128 + c0 + 4);
      float scl[8] = {s0.x, s0.y, s0.z, s0.w, s1.x, s1.y, s1.z, s1.w};
      float shf[8] = {h0.x, h0.y, h0.z, h0.w, h1.x, h1.y, h1.z, h1.w};
#pragma unroll
      for (int j = 0; j < 8; ++j) {
        float t = vals[j] * scl[j] + shf[j];
        vals[j] = t > 0.f ? t : 0.1f * t;
      }
    }
#pragma unroll
    for (int j = 0; j < 8; ++j) {
      ushort_t hh = f2bf(vals[j]);
      ah[ks][j] = (short)hh;
      al[ks][j] = (short)f2bf(vals[j] - bf2f(hh));
    }
  }
  __syncthreads();

  f32x4 acc[DOUT / 16];
#pragma unroll
  for (int ct = 0; ct < DOUT / 16; ++ct) acc[ct] = f32x4{0.f, 0.f, 0.f, 0.f};

#pragma unroll
  for (int ks = 0; ks < 4; ++ks) {
#pragma unroll
    for (int ct = 0; ct < DOUT / 16; ++ct) {
      int r = ct * 16 + col;
      bf16x8 bh = *reinterpret_cast<const bf16x8*>(&WHs[r][ks * 32 + g * 8]);
      bf16x8 bl = *reinterpret_cast<const bf16x8*>(&WLs[r][ks * 32 + g * 8]);
      acc[ct] = __builtin_amdgcn_mfma_f32_16x16x32_bf16(ah[ks], bh, acc[ct], 0, 0, 0);
      acc[ct] = __builtin_amdgcn_mfma_f32_16x16x32_bf16(al[ks], bh, acc[ct], 0, 0, 0);
      acc[ct] = __builtin_amdgcn_mfma_f32_16x16x32_bf16(ah[ks], bl, acc[ct], 0, 0, 0);
    }
  }
  // D layout: row = g*4 + r, col = ct*16 + (lane&15)
#pragma unroll
  for (int r = 0; r < 4; ++r) {
    int orow = brow + g * 4 + r;
    if (orow < N) {
#pragma unroll
      for (int ct = 0; ct < DOUT / 16; ++ct)
        C[(size_t)orow * DOUT + ct * 16 + col] = f2bf(acc[ct][r]);
    }
  }
}

// ---------------------------------------------------------------------------
// aggregation D=128: one wave/node, lane owns packed channels (2l,2l+1).
// ---------------------------------------------------------------------------
__global__ __launch_bounds__(256) void k_agg128(
    const ushort_t* __restrict__ t, const int* __restrict__ row_ptr,
    const int2* __restrict__ pk, const float* __restrict__ dis,
    const float* __restrict__ bias, float* __restrict__ out, int N) {
  int node = __builtin_amdgcn_readfirstlane(blockIdx.x * 4 + (threadIdx.x >> 6));
  int lane = threadIdx.x & 63;
  if (node >= N) return;
  const uint_t* t2 = reinterpret_cast<const uint_t*>(t);
  float d = dis[node];
  float self = d * d;
  uint_t sv = t2[(size_t)node * 64 + lane];
  float acc0 = bflo(sv) * self;
  float acc1 = bfhi(sv) * self;
  int beg = row_ptr[node], end = row_ptr[node + 1];
  float x0 = 0.f, y0 = 0.f, x1 = 0.f, y1 = 0.f;
  float x2 = 0.f, y2 = 0.f, x3 = 0.f, y3 = 0.f;
  int e = beg;
  for (; e + 4 <= end; e += 4) {
    int2 p0 = pk[e], p1 = pk[e + 1], p2 = pk[e + 2], p3 = pk[e + 3];
    float w0 = __int_as_float(p0.y), w1 = __int_as_float(p1.y);
    float w2 = __int_as_float(p2.y), w3 = __int_as_float(p3.y);
    uint_t v0 = t2[(size_t)p0.x * 64 + lane];
    uint_t v1 = t2[(size_t)p1.x * 64 + lane];
    uint_t v2 = t2[(size_t)p2.x * 64 + lane];
    uint_t v3 = t2[(size_t)p3.x * 64 + lane];
    x0 += w0 * bflo(v0); y0 += w0 * bfhi(v0);
    x1 += w1 * bflo(v1); y1 += w1 * bfhi(v1);
    x2 += w2 * bflo(v2); y2 += w2 * bfhi(v2);
    x3 += w3 * bflo(v3); y3 += w3 * bfhi(v3);
  }
  for (; e < end; ++e) {
    int2 p = pk[e];
    float w = __int_as_float(p.y);
    uint_t v = t2[(size_t)p.x * 64 + lane];
    x0 += w * bflo(v); y0 += w * bfhi(v);
  }
  acc0 += (x0 + x1) + (x2 + x3);
  acc1 += (y0 + y1) + (y2 + y3);
  float2 b = reinterpret_cast<const float2*>(bias)[lane];
  reinterpret_cast<float2*>(out)[(size_t)node * 64 + lane] =
      make_float2(acc0 + b.x, acc1 + b.y);
}

// aggregation D=64 + bias + L2 row-normalize -> d_out
__global__ __launch_bounds__(256) void k_agg64_norm(
    const ushort_t* __restrict__ t, const int* __restrict__ row_ptr,
    const int2* __restrict__ pk, const float* __restrict__ dis,
    const float* __restrict__ b3, float* __restrict__ out, int N) {
  int node = __builtin_amdgcn_readfirstlane(blockIdx.x * 4 + (threadIdx.x >> 6));
  int lane = threadIdx.x & 63;
  if (node >= N) return;
  float d = dis[node];
  float acc = bf2f(t[(size_t)node * 64 + lane]) * d * d;
  int beg = row_ptr[node], end = row_ptr[node + 1];
  float x0 = 0.f, x1 = 0.f, x2 = 0.f, x3 = 0.f;
  int e = beg;
  for (; e + 4 <= end; e += 4) {
    int2 p0 = pk[e], p1 = pk[e + 1], p2 = pk[e + 2], p3 = pk[e + 3];
    x0 += __int_as_float(p0.y) * bf2f(t[(size_t)p0.x * 64 + lane]);
    x1 += __int_as_float(p1.y) * bf2f(t[(size_t)p1.x * 64 + lane]);
    x2 += __int_as_float(p2.y) * bf2f(t[(size_t)p2.x * 64 + lane]);
    x3 += __int_as_float(p3.y) * bf2f(t[(size_t)p3.x * 64 + lane]);
  }
  for (; e < end; ++e) {
    int2 p = pk[e];
    x0 += __int_as_float(p.y) * bf2f(t[(size_t)p.x * 64 + lane]);
  }
  acc += (x0 + x1) + (x2 + x3);
  acc += b3[lane];
  float sq = acc * acc;
#pragma unroll
  for (int off = 32; off; off >>= 1) sq += __shfl_xor(sq, off, 64);
  float nrm = sqrtf(sq);
  out[(size_t)node * 64 + lane] = acc / fmaxf(nrm, 1e-12f);
}

// BN stats
__global__ void k_bn_partial(const float* __restrict__ h, float* __restrict__ sums,
                             int N) {
  int c = threadIdx.x & 127;
  int half = threadIdx.x >> 7;
  float s = 0.f, q = 0.f;
  for (int r = blockIdx.x * 2 + half; r < N; r += gridDim.x * 2) {
    float v = h[(size_t)r * 128 + c];
    s += v; q += v * v;
  }
  atomicAdd(&sums[c], s);
  atomicAdd(&sums[128 + c], q);
}

__global__ void k_bn_final(const float* __restrict__ sums, const float* __restrict__ g,
                           const float* __restrict__ be, float* __restrict__ scsh,
                           int N) {
  int c = threadIdx.x;  // 128
  float inv_n = 1.0f / (float)N;
  float mu = sums[c] * inv_n;
  float var = sums[128 + c] * inv_n - mu * mu;
  float sc = g[c] * rsqrtf(var + 1e-5f);
  scsh[c] = sc;
  scsh[128 + c] = be[c] - mu * sc;
}

// ---------------------------------------------------------------------------

extern "C" void kernel_launch(void* const* d_in, const int* in_sizes, int n_in,
                              void* d_out, int out_size, void* d_ws, size_t ws_size,
                              hipStream_t stream) {
  const float* x  = (const float*)d_in[0];
  const int*   ei = (const int*)d_in[1];
  const float* ew = (const float*)d_in[2];
  const float* W1 = (const float*)d_in[3];
  const float* b1 = (const float*)d_in[4];
  const float* g1 = (const float*)d_in[5];
  const float* be1= (const float*)d_in[6];
  const float* W2 = (const float*)d_in[7];
  const float* b2 = (const float*)d_in[8];
  const float* g2 = (const float*)d_in[9];
  const float* be2= (const float*)d_in[10];
  const float* W3 = (const float*)d_in[11];
  const float* b3 = (const float*)d_in[12];

  const int N = in_sizes[0] / 128;   // 100000
  const int E = in_sizes[2];         // 1600000
  const int* src = ei;
  const int* dst = ei + E;

  char* p = (char*)d_ws;
  auto alloc = [&](size_t bytes) -> void* {
    void* r = (void*)p;
    p += (bytes + 255) & ~(size_t)255;
    return r;
  };
  int*   count    = (int*)alloc((size_t)N * 4);
  int*   row_ptr  = (int*)alloc((size_t)(N + 1) * 4);
  int*   rank     = (int*)alloc((size_t)E * 4);
  int*   part     = (int*)alloc(256 * 4);
  float* dis      = (float*)alloc((size_t)N * 4);
  int2*  pk       = (int2*)alloc((size_t)E * 8);
  ushort_t* t_buf = (ushort_t*)alloc((size_t)N * 128 * 2);
  float* h_buf    = (float*)alloc((size_t)N * 128 * 4);
  ushort_t* w1th  = (ushort_t*)alloc(128 * 128 * 2);
  ushort_t* w1tl  = (ushort_t*)alloc(128 * 128 * 2);
  ushort_t* w2th  = (ushort_t*)alloc(128 * 128 * 2);
  ushort_t* w2tl  = (ushort_t*)alloc(128 * 128 * 2);
  ushort_t* w3th  = (ushort_t*)alloc(128 * 64 * 2);
  ushort_t* w3tl  = (ushort_t*)alloc(128 * 64 * 2);
  float* bnsum    = (float*)alloc(512 * 4);
  float* scsh1    = (float*)alloc(256 * 4);
  float* scsh2    = (float*)alloc(256 * 4);
  (void)ws_size; (void)n_in; (void)out_size;

  const int gN = (N + 255) / 256;
  const int gE = (E + 255) / 256;
  const int scanBlocks = (N + 1023) / 1024;
  const int gemmBlocks = (N + 63) / 64;
  const int aggBlocks = (N + 3) / 4;

  // graph build: 1 atomic/edge (count+rank), then atomic-free scatter
  k_init<<<gN, 256, 0, stream>>>(count, bnsum, N);
  k_count_rank<<<gE, 256, 0, stream>>>(dst, count, rank, E);
  k_scan_part<<<scanBlocks, 256, 0, stream>>>(count, part, N);
  k_scan_top<<<1, 256, 0, stream>>>(part, scanBlocks, row_ptr + N);
  k_scan_bot<<<scanBlocks, 256, 0, stream>>>(count, part, row_ptr, N);
  k_scatter<<<gE, 256, 0, stream>>>(src, dst, ew, row_ptr, rank, pk, E);
  k_degdis<<<gN, 256, 0, stream>>>(pk, row_ptr, dis, N);
  k_normw<<<gN, 256, 0, stream>>>(pk, row_ptr, dis, N);

  // weight prep (tiny)
  k_prepw<<<64, 256, 0, stream>>>(W1, w1th, w1tl, 128, 128 * 128);
  k_prepw<<<64, 256, 0, stream>>>(W2, w2th, w2tl, 128, 128 * 128);
  k_prepw<<<32, 256, 0, stream>>>(W3, w3th, w3tl, 64, 128 * 64);

  // layer 1
  k_gemm_mfma<128, false><<<gemmBlocks, 256, 0, stream>>>(x, nullptr, w1th, w1tl,
                                                          t_buf, N);
  k_agg128<<<aggBlocks, 256, 0, stream>>>(t_buf, row_ptr, pk, dis, b1, h_buf, N);
  k_bn_partial<<<512, 256, 0, stream>>>(h_buf, bnsum, N);
  k_bn_final<<<1, 128, 0, stream>>>(bnsum, g1, be1, scsh1, N);

  // layer 2
  k_gemm_mfma<128, true><<<gemmBlocks, 256, 0, stream>>>(h_buf, scsh1, w2th, w2tl,
                                                         t_buf, N);
  k_agg128<<<aggBlocks, 256, 0, stream>>>(t_buf, row_ptr, pk, dis, b2, h_buf, N);
  k_bn_partial<<<512, 256, 0, stream>>>(h_buf, bnsum + 256, N);
  k_bn_final<<<1, 128, 0, stream>>>(bnsum + 256, g2, be2, scsh2, N);

  // layer 3
  k_gemm_mfma<64, true><<<gemmBlocks, 256, 0, stream>>>(h_buf, scsh2, w3th, w3tl,
                                                        t_buf, N);
  k_agg64_norm<<<aggBlocks, 256, 0, stream>>>(t_buf, row_ptr, pk, dis, b3,
                                              (float*)d_out, N);
}